// Round 3
// baseline (168.853 us; speedup 1.0000x reference)
//
#include <hip/hip_runtime.h>

// Problem constants (reference: B=8, T=2048, C=1024, H=64)
#define B_ 8
#define T_ 2048
#define C_ 1024
#define H_ 64

typedef __bf16 bf16x8 __attribute__((ext_vector_type(8)));
typedef float  f32x4  __attribute__((ext_vector_type(4)));
typedef unsigned short u16x8 __attribute__((ext_vector_type(8)));

// round-half-up f32 -> bf16 bits
__device__ __forceinline__ unsigned short f2bf(float f) {
    unsigned u = __builtin_bit_cast(unsigned, f);
    u += 0x8000u;
    return (unsigned short)(u >> 16);
}

__device__ __forceinline__ float bf2f(unsigned short v) {
    unsigned u = ((unsigned)v) << 16;
    return __builtin_bit_cast(float, u);
}

__device__ __forceinline__ unsigned pack2(float lo, float hi) {
    unsigned a = __builtin_bit_cast(unsigned, lo) + 0x8000u;
    unsigned b = __builtin_bit_cast(unsigned, hi) + 0x8000u;
    return (a >> 16) | (b & 0xffff0000u);
}

union U8 { unsigned u32[4]; u16x8 v; };

__device__ __forceinline__ u16x8 cvt8(float4 f0, float4 f1) {
    U8 r;
    r.u32[0] = pack2(f0.x, f0.y);
    r.u32[1] = pack2(f0.z, f0.w);
    r.u32[2] = pack2(f1.x, f1.y);
    r.u32[3] = pack2(f1.z, f1.w);
    return r.v;
}

__device__ __forceinline__ bf16x8 load8_bf(const unsigned short* p) {
    return __builtin_bit_cast(bf16x8, *(const u16x8*)p);
}

// Fragment-major layouts (contiguous 1KB-per-wave loads):
//   Qf/Kf[b][t16][part][l16*32 + quad*8 + j]   (t16 = seq/16, part = h/32)
//   Vf[b][s32][ht][l16*32 + quad*8 + j]        (s32 = seq/32, ht = h/16)
//   Wtf[nt][kk][l16*32 + quad*8 + j]           (nt = ncol/16 of 192, kk = c/32)

// ---------------------------------------------------------------------------
// Kernel 0: pack Wq,Wk,Wv (fp32 [C][H]) straight into fragment-major Wtf.
// ---------------------------------------------------------------------------
__global__ void cast_weights(const float* __restrict__ Wq,
                             const float* __restrict__ Wk,
                             const float* __restrict__ Wv,
                             unsigned short* __restrict__ Wtf) {
    int idx = blockIdx.x * blockDim.x + threadIdx.x;   // 0 .. 192*1024-1
    int n   = idx % 192;        // global out col
    int c   = idx / 192;        // k index
    int w   = n >> 6;
    int h   = n & 63;
    const float* W = (w == 0) ? Wq : (w == 1) ? Wk : Wv;
    int nt = n >> 4, l16 = n & 15;
    int kk = c >> 5, quad = (c >> 3) & 3, j = c & 7;
    Wtf[(size_t)(nt * 32 + kk) * 512 + l16 * 32 + quad * 8 + j] =
        f2bf(W[(size_t)c * H_ + h]);
}

// ---------------------------------------------------------------------------
// Kernel 1: fused QKV projection, v10 — NO LDS STAGING.
// v8/v9 were both 44 us with VGPR=44: the compiler serialized the staging
// loop into 8 sequential HBM round-trips (load->vmcnt(0)->cvt->ds_write)
// because the unrolled load payload (64 VGPR) exceeded its budget; the same
// applied to the k-loop's 12 unrolled B loads. Exposed-latency chains, not
// occupancy/BW, were the invariant.
// v10: a lane's 16x16x32 A-fragment is 8 CONTIGUOUS fp32 of one x-row =
// two float4 global loads. Stream x global->reg->cvt->MFMA directly: no
// staging phase, no barriers in the main loop, every load an independent
// affine-address stream. Block = 32 rows x 192 cols, 4 waves: wave =
// 1 m-strip x 6 n-tiles (x re-read only 2x, L1/L2-hot; B traffic 192 MB
// from L2). launch_bounds(256,3) -> ~170 VGPR budget so unroll-2 holds
// 4 x-loads + 12 B-loads in flight. LDS = 12 KB epilogue buffer only
// (a 32-row block emits a full V s32-tile).
// ---------------------------------------------------------------------------
__global__ __launch_bounds__(256, 3) void qkv_proj(
        const float* __restrict__ x,
        const unsigned short* __restrict__ Wtf,
        unsigned short* __restrict__ Qf,
        unsigned short* __restrict__ Kf,
        unsigned short* __restrict__ Vf) {
    __shared__ __attribute__((aligned(16))) unsigned short E[12 * 512]; // 12 KB

    const int tid   = threadIdx.x;
    const int w     = tid >> 6;
    const int strip = w & 1;      // which 16-row strip of the 32-row block
    const int nh    = w >> 1;     // which 6-n-tile half of the 192 cols
    const int lane  = tid & 63;
    const int l16   = lane & 15;
    const int quad  = lane >> 4;
    const size_t r0 = (size_t)blockIdx.x * 32;
    const int bb    = (int)(r0 >> 11);
    const int tloc0 = (int)(r0 & (T_ - 1));
    const int t16_0 = tloc0 >> 4;
    const int s32   = tloc0 >> 5;

    f32x4 acc[6];
#pragma unroll
    for (int i = 0; i < 6; i++) acc[i] = (f32x4){0.f, 0.f, 0.f, 0.f};

    // lane's A-fragment source: x[r0 + strip*16 + l16][kk*32 + quad*8 .. +8]
    const float* xp = x + (r0 + strip * 16 + l16) * C_ + quad * 8;
    const unsigned short* wp = Wtf + (size_t)(nh * 6 * 32) * 512
                               + l16 * 32 + quad * 8;

#pragma unroll 2
    for (int kk = 0; kk < 32; kk++) {
        float4 f0 = *(const float4*)(xp + kk * 32);
        float4 f1 = *(const float4*)(xp + kk * 32 + 4);
        bf16x8 a0 = __builtin_bit_cast(bf16x8, cvt8(f0, f1));
#pragma unroll
        for (int i = 0; i < 6; i++) {
            bf16x8 b = load8_bf(wp + (size_t)(i * 32 + kk) * 512);
            acc[i] = __builtin_amdgcn_mfma_f32_16x16x32_bf16(a0, b, acc[i], 0, 0, 0);
        }
    }

    // ---- epilogue: assemble fragment-major chunks in LDS, coalesced copy out
    // acc[i] element (l16, quad, r) = out[r0 + strip*16 + quad*4 + r][nt*16 + l16],
    // nt = nh*6 + i.  E: Q 4x512 | K 4x512 | V 4x512.
#pragma unroll
    for (int i = 0; i < 6; i++) {
        int nt = nh * 6 + i;
#pragma unroll
        for (int r = 0; r < 4; r++) {
            unsigned short bv = f2bf(acc[i][r]);
            int off;
            if (nt < 4) {                // Q: chunk = strip*2 + part
                off = (strip * 2 + (nt >> 1)) * 512 +
                      (quad * 4 + r) * 32 + (nt & 1) * 16 + l16;
            } else if (nt < 8) {         // K
                int nk = nt - 4;
                off = 2048 + (strip * 2 + (nk >> 1)) * 512 +
                      (quad * 4 + r) * 32 + (nk & 1) * 16 + l16;
            } else {                     // V (transposed): h-major, s minor
                int ht = nt - 8;
                off = 4096 + ht * 512 + l16 * 32 + strip * 16 + quad * 4 + r;
            }
            E[off] = bv;
        }
    }
    __syncthreads();

    // 12 chunks x 64 granules; 3 granule copies per thread
#pragma unroll
    for (int c3 = 0; c3 < 3; c3++) {
        int gi = c3 * 256 + tid;         // 0..767
        int ch = gi >> 6;
        int g  = gi & 63;
        unsigned short* dst;
        if (ch < 4) {
            dst = Qf + ((size_t)(bb * 128 + t16_0 + (ch >> 1)) * 2 + (ch & 1)) * 512;
        } else if (ch < 8) {
            int c2 = ch - 4;
            dst = Kf + ((size_t)(bb * 128 + t16_0 + (c2 >> 1)) * 2 + (c2 & 1)) * 512;
        } else {
            dst = Vf + ((size_t)(bb * 64 + s32) * 4 + (ch - 8)) * 512;
        }
        *(u16x8*)(dst + g * 8) = *(const u16x8*)(&E[ch * 512 + g * 8]);
    }
}

// ---------------------------------------------------------------------------
// Kernel 2: flash attention, v8 (32 q-rows/block, 4-way KV split).
// Grid = B * T/32 = 512 blocks x 256 threads, XCD batch-affinity (b = blk&7).
// Two q-groups per block share every K/V fragment load (2x arithmetic
// intensity) and total KV tile re-read traffic halves vs v7.
// ---------------------------------------------------------------------------
#define PROW 33   // u32 per P^T row
#define OMS2 66   // u16 per O-merge row

__global__ __launch_bounds__(256) void attn(
        const unsigned short* __restrict__ Qf,
        const unsigned short* __restrict__ Kf,
        const unsigned short* __restrict__ Vf,
        float* __restrict__ out) {
    __shared__ unsigned int ps_[4 * 32 * PROW];     // 16.9 KB
    __shared__ unsigned short Om_[4 * 32 * OMS2];   // 16.9 KB
    __shared__ float mred_[4][32];
    __shared__ float lred_[4][32];

    const int tid  = threadIdx.x;
    const int wave = tid >> 6;            // KV-split index 0..3
    const int lane = tid & 63;
    const int l16  = lane & 15;
    const int quad = lane >> 4;
    const int b    = blockIdx.x & 7;      // XCD-affinity: batch = XCD
    const int qt32 = blockIdx.x >> 3;     // 0..63
    const int q0   = qt32 * 32;
    const int tdiag = qt32 >> 1;          // diagonal 64-key tile index

    const int loff = l16 * 32 + quad * 8;

    // Q as B-operand, two q-groups
    bf16x8 qf[2][2];
#pragma unroll
    for (int qg = 0; qg < 2; qg++) {
        const unsigned short* Qfb = Qf + (size_t)((b * 128 + qt32 * 2 + qg) * 2) * 512;
        qf[qg][0] = load8_bf(Qfb + loff);
        qf[qg][1] = load8_bf(Qfb + 512 + loff);
    }

    f32x4 o[8];   // [qg*4 + ht]
#pragma unroll
    for (int i = 0; i < 8; i++) o[i] = (f32x4){0.f, 0.f, 0.f, 0.f};
    float m_run[2] = {-1e30f, -1e30f}, l_run[2] = {0.f, 0.f};

    const float scale = 0.125f;  // 1/sqrt(H)
    const unsigned short* Kfb = Kf + (size_t)b * 128 * 1024;
    const unsigned short* Vfb = Vf + (size_t)b * 64 * 2048;
    unsigned int* Pw = &ps_[wave * 32 * PROW];

    for (int t = wave; t <= tdiag; t += 4) {
        // V^T A-frags: contiguous 1KB loads, issued EARLY (softmax-independent)
        bf16x8 vf[8];
#pragma unroll
        for (int ks = 0; ks < 2; ks++)
#pragma unroll
            for (int ht = 0; ht < 4; ht++)
                vf[ht * 2 + ks] = load8_bf(
                    Vfb + ((size_t)(t * 2 + ks) * 4 + ht) * 512 + loff);

        // S^T = K * Q^T for both q-groups (K frags shared)
        f32x4 s[2][4];
#pragma unroll
        for (int nt = 0; nt < 4; nt++) {
            const unsigned short* kp = Kfb + (size_t)(t * 4 + nt) * 1024;
            bf16x8 kf0 = load8_bf(kp + loff);
            bf16x8 kf1 = load8_bf(kp + 512 + loff);
#pragma unroll
            for (int qg = 0; qg < 2; qg++) {
                f32x4 z = (f32x4){0.f, 0.f, 0.f, 0.f};
                z = __builtin_amdgcn_mfma_f32_16x16x32_bf16(kf0, qf[qg][0], z, 0, 0, 0);
                z = __builtin_amdgcn_mfma_f32_16x16x32_bf16(kf1, qf[qg][1], z, 0, 0, 0);
                s[qg][nt] = z;   // S^T[s = t*64+nt*16+quad*4+r][q = q0+qg*16+l16]
            }
        }

#pragma unroll
        for (int qg = 0; qg < 2; qg++)
#pragma unroll
            for (int nt = 0; nt < 4; nt++)
#pragma unroll
                for (int r = 0; r < 4; r++) s[qg][nt][r] *= scale;

        if (t == tdiag) {   // causal: mask s > q
#pragma unroll
            for (int qg = 0; qg < 2; qg++) {
                int q = q0 + qg * 16 + l16;
#pragma unroll
                for (int nt = 0; nt < 4; nt++)
#pragma unroll
                    for (int r = 0; r < 4; r++) {
                        int key = t * 64 + nt * 16 + quad * 4 + r;
                        if (key > q) s[qg][nt][r] = -1e30f;
                    }
            }
        }

        // per-lane softmax per q-group: in-lane tree + 2 cross-quad shuffles
#pragma unroll
        for (int qg = 0; qg < 2; qg++) {
            float m0 = fmaxf(fmaxf(s[qg][0][0], s[qg][0][1]), fmaxf(s[qg][0][2], s[qg][0][3]));
            float m1 = fmaxf(fmaxf(s[qg][1][0], s[qg][1][1]), fmaxf(s[qg][1][2], s[qg][1][3]));
            float m2 = fmaxf(fmaxf(s[qg][2][0], s[qg][2][1]), fmaxf(s[qg][2][2], s[qg][2][3]));
            float m3 = fmaxf(fmaxf(s[qg][3][0], s[qg][3][1]), fmaxf(s[qg][3][2], s[qg][3][3]));
            float mx = fmaxf(fmaxf(m0, m1), fmaxf(m2, m3));
            mx = fmaxf(mx, __shfl_xor(mx, 16));
            mx = fmaxf(mx, __shfl_xor(mx, 32));
            const float m_new = fmaxf(m_run[qg], mx);
            const float alpha = __expf(m_run[qg] - m_new);
            m_run[qg] = m_new;

            float rs = 0.f;
#pragma unroll
            for (int nt = 0; nt < 4; nt++) {
#pragma unroll
                for (int i = 0; i < 2; i++) {
                    float p0 = __expf(s[qg][nt][2 * i]     - m_new);
                    float p1 = __expf(s[qg][nt][2 * i + 1] - m_new);
                    rs += p0 + p1;
                    Pw[(qg * 16 + l16) * PROW + nt * 8 + quad * 2 + i] = pack2(p0, p1);
                }
            }
            rs += __shfl_xor(rs, 16);
            rs += __shfl_xor(rs, 32);
            l_run[qg] = l_run[qg] * alpha + rs;

#pragma unroll
            for (int ht = 0; ht < 4; ht++)
#pragma unroll
                for (int r = 0; r < 4; r++) o[qg * 4 + ht][r] *= alpha;
        }

        // O^T += V^T * P^T (V frags shared across q-groups)
#pragma unroll
        for (int ks = 0; ks < 2; ks++) {
#pragma unroll
            for (int qg = 0; qg < 2; qg++) {
                bf16x8 pB = __builtin_bit_cast(bf16x8,
                    *(const u16x8*)(&Pw[(qg * 16 + l16) * PROW + ks * 16 + quad * 4]));
#pragma unroll
                for (int ht = 0; ht < 4; ht++)
                    o[qg * 4 + ht] = __builtin_amdgcn_mfma_f32_16x16x32_bf16(
                        vf[ht * 2 + ks], pB, o[qg * 4 + ht], 0, 0, 0);
            }
        }
    }

    // ---- 4-way LSE merge (O partials bf16) ----
#pragma unroll
    for (int qg = 0; qg < 2; qg++) {
#pragma unroll
        for (int ht = 0; ht < 4; ht++)
#pragma unroll
            for (int r = 0; r < 4; r++)
                Om_[(wave * 32 + qg * 16 + l16) * OMS2 + ht * 16 + quad * 4 + r] =
                    f2bf(o[qg * 4 + ht][r]);
        if (quad == 0) {
            mred_[wave][qg * 16 + l16] = m_run[qg];
            lred_[wave][qg * 16 + l16] = l_run[qg];
        }
    }
    __syncthreads();

    // finalize: thread -> (q, h); coalesced out write
    const int hcol = tid & 63;
    const int qr0  = tid >> 6;   // 0..3
#pragma unroll
    for (int qq = 0; qq < 8; qq++) {
        const int q = qr0 + qq * 4;
        float M = -1e30f;
#pragma unroll
        for (int w = 0; w < 4; w++) M = fmaxf(M, mred_[w][q]);
        float lt = 0.f, ov = 0.f;
#pragma unroll
        for (int w = 0; w < 4; w++) {
            float e = __expf(mred_[w][q] - M);
            lt += e * lred_[w][q];
            ov += e * bf2f(Om_[(w * 32 + q) * OMS2 + hcol]);
        }
        out[((size_t)b * T_ + q0 + q) * H_ + hcol] = ov / lt;
    }
}

// ---------------------------------------------------------------------------
extern "C" void kernel_launch(void* const* d_in, const int* in_sizes, int n_in,
                              void* d_out, int out_size, void* d_ws, size_t ws_size,
                              hipStream_t stream) {
    const float* x  = (const float*)d_in[0];
    const float* Wq = (const float*)d_in[1];
    const float* Wk = (const float*)d_in[2];
    const float* Wv = (const float*)d_in[3];
    float* out = (float*)d_out;

    unsigned short* Qf  = (unsigned short*)d_ws;
    unsigned short* Kf  = Qf + (size_t)B_ * T_ * H_;
    unsigned short* Vf  = Kf + (size_t)B_ * T_ * H_;
    unsigned short* Wtf = Vf + (size_t)B_ * T_ * H_;

    cast_weights<<<(192 * C_) / 256, 256, 0, stream>>>(Wq, Wk, Wv, Wtf);
    qkv_proj<<<B_ * T_ / 32, 256, 0, stream>>>(x, Wtf, Qf, Kf, Vf);
    attn<<<B_ * (T_ / 32), 256, 0, stream>>>(Qf, Kf, Vf, out);
}

// Round 4
// 138.067 us; speedup vs baseline: 1.2230x; 1.2230x over previous
//
#include <hip/hip_runtime.h>

// Problem constants (reference: B=8, T=2048, C=1024, H=64)
#define B_ 8
#define T_ 2048
#define C_ 1024
#define H_ 64

typedef __bf16 bf16x8 __attribute__((ext_vector_type(8)));
typedef float  f32x4  __attribute__((ext_vector_type(4)));
typedef unsigned short u16x8 __attribute__((ext_vector_type(8)));

// round-half-up f32 -> bf16 bits
__device__ __forceinline__ unsigned short f2bf(float f) {
    unsigned u = __builtin_bit_cast(unsigned, f);
    u += 0x8000u;
    return (unsigned short)(u >> 16);
}

__device__ __forceinline__ float bf2f(unsigned short v) {
    unsigned u = ((unsigned)v) << 16;
    return __builtin_bit_cast(float, u);
}

__device__ __forceinline__ unsigned pack2(float lo, float hi) {
    unsigned a = __builtin_bit_cast(unsigned, lo) + 0x8000u;
    unsigned b = __builtin_bit_cast(unsigned, hi) + 0x8000u;
    return (a >> 16) | (b & 0xffff0000u);
}

union U8 { unsigned u32[4]; u16x8 v; };

__device__ __forceinline__ u16x8 cvt8(float4 f0, float4 f1) {
    U8 r;
    r.u32[0] = pack2(f0.x, f0.y);
    r.u32[1] = pack2(f0.z, f0.w);
    r.u32[2] = pack2(f1.x, f1.y);
    r.u32[3] = pack2(f1.z, f1.w);
    return r.v;
}

__device__ __forceinline__ bf16x8 load8_bf(const unsigned short* p) {
    return __builtin_bit_cast(bf16x8, *(const u16x8*)p);
}

// Async global->LDS, 16B per lane, no destination VGPRs (vmcnt-counted).
__device__ __forceinline__ void gload_lds16(const float* g, float* l) {
    __builtin_amdgcn_global_load_lds(
        (const __attribute__((address_space(1))) unsigned int*)g,
        (__attribute__((address_space(3))) unsigned int*)l, 16, 0, 0);
}

// Fragment-major layouts (contiguous 1KB-per-wave loads):
//   Qf/Kf[b][t16][part][l16*32 + quad*8 + j]   (t16 = seq/16, part = h/32)
//   Vf[b][s32][ht][l16*32 + quad*8 + j]        (s32 = seq/32, ht = h/16)
//   Wtf[nt][kk][l16*32 + quad*8 + j]           (nt = ncol/16 of 192, kk = c/32)

// ---------------------------------------------------------------------------
// Kernel 0: pack Wq,Wk,Wv (fp32 [C][H]) straight into fragment-major Wtf.
// ---------------------------------------------------------------------------
__global__ void cast_weights(const float* __restrict__ Wq,
                             const float* __restrict__ Wk,
                             const float* __restrict__ Wv,
                             unsigned short* __restrict__ Wtf) {
    int idx = blockIdx.x * blockDim.x + threadIdx.x;   // 0 .. 192*1024-1
    int n   = idx % 192;        // global out col
    int c   = idx / 192;        // k index
    int w   = n >> 6;
    int h   = n & 63;
    const float* W = (w == 0) ? Wq : (w == 1) ? Wk : Wv;
    int nt = n >> 4, l16 = n & 15;
    int kk = c >> 5, quad = (c >> 3) & 3, j = c & 7;
    Wtf[(size_t)(nt * 32 + kk) * 512 + l16 * 32 + quad * 8 + j] =
        f2bf(W[(size_t)c * H_ + h]);
}

// ---------------------------------------------------------------------------
// Kernel 1: fused QKV projection, v11 — ASYNC global_load_lds staging.
// v8/v9/v10 were all latency-serialized: any load needing destination VGPRs
// got vmcnt-drained by the compiler (VGPR_Count 76/44/32), exposing full
// HBM/L2 latency per step; occupancy doubling (v9) changed nothing.
// v11 stages x fp32 via __builtin_amdgcn_global_load_lds (NO dest VGPRs):
// each wave issues 16 back-to-back 1KB copies -> one amortized HBM
// round-trip, then a barrier, then 32 uninterrupted k-steps.
// LDS = [16][1024] fp32 (64 KB, 2 blocks/CU). Global source is
// pre-swizzled at 16B granularity (slot = g16 ^ (row&7), LDS dest linear
// per m104/m173) so the fragment ds_read_b128 pairs are bank-conflict-free
// (2-way, which is free). bf16 conversion happens at fragment-read time
// (4 pack2 per k-step). Wave = 3 n-tiles x 16 rows, acc[3]; per k-step:
// 2 ds_read_b128 + cvt + 3 contiguous 1KB Wtf loads (L1/L2-hot) + 3 MFMA.
// ---------------------------------------------------------------------------
__global__ __launch_bounds__(256, 2) void qkv_proj(
        const float* __restrict__ x,
        const unsigned short* __restrict__ Wtf,
        unsigned short* __restrict__ Qf,
        unsigned short* __restrict__ Kf,
        unsigned short* __restrict__ Vf) {
    __shared__ __attribute__((aligned(16))) float Axs[16 * 1024]; // 64 KB

    const int tid  = threadIdx.x;
    const int ns   = tid >> 6;           // wave = n-quarter (3 n-tiles)
    const int lane = tid & 63;
    const int l16  = lane & 15;
    const int quad = lane >> 4;
    const size_t r0 = (size_t)blockIdx.x * 16;
    const int bb     = (int)(r0 >> 11);
    const int tloc0  = (int)(r0 & (T_ - 1));
    const int t16_0  = tloc0 >> 4;
    const int s32    = tloc0 >> 5;
    const int half16 = t16_0 & 1;        // which 16-row half of the s32 V-tile

    // ---- async staging: 64 x 1KB issues (16 per wave), swizzled source ----
    // LDS slot s (16B) of row r holds global granule16  g = s ^ (r&7).
#pragma unroll
    for (int jj = 0; jj < 16; jj++) {
        int j   = ns * 16 + jj;          // issue 0..63
        int row = j >> 2;                // 0..15
        int S0  = (j & 3) * 64;          // 16B-slot base within the row
        int g   = (S0 + lane) ^ (row & 7);   // global granule16 for this lane
        const float* gp = x + (r0 + row) * C_ + g * 4;
        float* lp = &Axs[row * 1024 + S0 * 4];   // wave-uniform base
        gload_lds16(gp, lp);
    }

    f32x4 acc[3];
#pragma unroll
    for (int i = 0; i < 3; i++) acc[i] = (f32x4){0.f, 0.f, 0.f, 0.f};

    const int xsw = l16 & 7;
    const unsigned short* wp = Wtf + (size_t)(ns * 3 * 32) * 512
                               + l16 * 32 + quad * 8;
    const float* Arow = &Axs[l16 * 1024];

    __syncthreads();                     // drains vmcnt(0): staging complete

    // ---- 32 k-steps, no further barriers ----
#pragma unroll 4
    for (int kk = 0; kk < 32; kk++) {
        int g0 = kk * 8 + quad * 2;      // even granule16 index of the frag
        float4 f0 = *(const float4*)(Arow + (size_t)((g0    ) ^ xsw) * 4);
        float4 f1 = *(const float4*)(Arow + (size_t)((g0 + 1) ^ xsw) * 4);
        bf16x8 a0 = __builtin_bit_cast(bf16x8, cvt8(f0, f1));
#pragma unroll
        for (int i = 0; i < 3; i++) {
            bf16x8 b = load8_bf(wp + (size_t)(i * 32 + kk) * 512);
            acc[i] = __builtin_amdgcn_mfma_f32_16x16x32_bf16(a0, b, acc[i], 0, 0, 0);
        }
    }

    // ---- epilogue (v9-verified): assemble fragment-major chunks in LDS ----
    __syncthreads();                     // all ds_reads done; reuse Axs as E
    unsigned short* E = (unsigned short*)Axs;  // Q 2x512 | K 2x512 | V 4x256
#pragma unroll
    for (int i = 0; i < 3; i++) {
        int nt = ns * 3 + i;
#pragma unroll
        for (int r = 0; r < 4; r++) {
            unsigned short bv = f2bf(acc[i][r]);
            int off;
            if (nt < 4) {                // Q, part = nt>>1
                off = (nt >> 1) * 512 + (quad * 4 + r) * 32 +
                      ((nt & 1) * 2 + (l16 >> 3)) * 8 + (l16 & 7);
            } else if (nt < 8) {         // K
                int nk = nt - 4;
                off = 1024 + (nk >> 1) * 512 + (quad * 4 + r) * 32 +
                      ((nk & 1) * 2 + (l16 >> 3)) * 8 + (l16 & 7);
            } else {                     // V (transposed): h-major, s minor
                int ht = nt - 8;
                off = 2048 + ht * 256 + l16 * 16 + quad * 4 + r;
            }
            E[off] = bv;
        }
    }
    __syncthreads();

    // Q/K: 4 chunks x 64 granules = 256 granule copies (1 per thread)
    {
        int ch = tid >> 6;               // 0..3
        int g  = tid & 63;
        unsigned short* dst = (ch < 2) ? Qf : Kf;
        int part = ch & 1;
        dst += ((size_t)(bb * 128 + t16_0) * 2 + part) * 512;
        *(u16x8*)(dst + g * 8) = *(const u16x8*)(&E[ch * 512 + g * 8]);
    }
    // V: 4 ht-chunks x 16 h-rows x 2 granules = 128 granule copies
    if (tid < 128) {
        int ht   = tid >> 5;             // 0..3
        int rr   = tid & 31;
        int l16v = rr >> 1;              // h within 16-tile
        int hh   = rr & 1;               // which 8-granule of the 16 s-cols
        unsigned short* dst = Vf + ((size_t)(bb * 64 + s32) * 4 + ht) * 512
                              + l16v * 32 + half16 * 16 + hh * 8;
        *(u16x8*)dst = *(const u16x8*)(&E[2048 + ht * 256 + l16v * 16 + hh * 8]);
    }
}

// ---------------------------------------------------------------------------
// Kernel 2: flash attention, v8 (32 q-rows/block, 4-way KV split).
// Grid = B * T/32 = 512 blocks x 256 threads, XCD batch-affinity (b = blk&7).
// Two q-groups per block share every K/V fragment load (2x arithmetic
// intensity) and total KV tile re-read traffic halves vs v7.
// ---------------------------------------------------------------------------
#define PROW 33   // u32 per P^T row
#define OMS2 66   // u16 per O-merge row

__global__ __launch_bounds__(256) void attn(
        const unsigned short* __restrict__ Qf,
        const unsigned short* __restrict__ Kf,
        const unsigned short* __restrict__ Vf,
        float* __restrict__ out) {
    __shared__ unsigned int ps_[4 * 32 * PROW];     // 16.9 KB
    __shared__ unsigned short Om_[4 * 32 * OMS2];   // 16.9 KB
    __shared__ float mred_[4][32];
    __shared__ float lred_[4][32];

    const int tid  = threadIdx.x;
    const int wave = tid >> 6;            // KV-split index 0..3
    const int lane = tid & 63;
    const int l16  = lane & 15;
    const int quad = lane >> 4;
    const int b    = blockIdx.x & 7;      // XCD-affinity: batch = XCD
    const int qt32 = blockIdx.x >> 3;     // 0..63
    const int q0   = qt32 * 32;
    const int tdiag = qt32 >> 1;          // diagonal 64-key tile index

    const int loff = l16 * 32 + quad * 8;

    // Q as B-operand, two q-groups
    bf16x8 qf[2][2];
#pragma unroll
    for (int qg = 0; qg < 2; qg++) {
        const unsigned short* Qfb = Qf + (size_t)((b * 128 + qt32 * 2 + qg) * 2) * 512;
        qf[qg][0] = load8_bf(Qfb + loff);
        qf[qg][1] = load8_bf(Qfb + 512 + loff);
    }

    f32x4 o[8];   // [qg*4 + ht]
#pragma unroll
    for (int i = 0; i < 8; i++) o[i] = (f32x4){0.f, 0.f, 0.f, 0.f};
    float m_run[2] = {-1e30f, -1e30f}, l_run[2] = {0.f, 0.f};

    const float scale = 0.125f;  // 1/sqrt(H)
    const unsigned short* Kfb = Kf + (size_t)b * 128 * 1024;
    const unsigned short* Vfb = Vf + (size_t)b * 64 * 2048;
    unsigned int* Pw = &ps_[wave * 32 * PROW];

    for (int t = wave; t <= tdiag; t += 4) {
        // V^T A-frags: contiguous 1KB loads, issued EARLY (softmax-independent)
        bf16x8 vf[8];
#pragma unroll
        for (int ks = 0; ks < 2; ks++)
#pragma unroll
            for (int ht = 0; ht < 4; ht++)
                vf[ht * 2 + ks] = load8_bf(
                    Vfb + ((size_t)(t * 2 + ks) * 4 + ht) * 512 + loff);

        // S^T = K * Q^T for both q-groups (K frags shared)
        f32x4 s[2][4];
#pragma unroll
        for (int nt = 0; nt < 4; nt++) {
            const unsigned short* kp = Kfb + (size_t)(t * 4 + nt) * 1024;
            bf16x8 kf0 = load8_bf(kp + loff);
            bf16x8 kf1 = load8_bf(kp + 512 + loff);
#pragma unroll
            for (int qg = 0; qg < 2; qg++) {
                f32x4 z = (f32x4){0.f, 0.f, 0.f, 0.f};
                z = __builtin_amdgcn_mfma_f32_16x16x32_bf16(kf0, qf[qg][0], z, 0, 0, 0);
                z = __builtin_amdgcn_mfma_f32_16x16x32_bf16(kf1, qf[qg][1], z, 0, 0, 0);
                s[qg][nt] = z;   // S^T[s = t*64+nt*16+quad*4+r][q = q0+qg*16+l16]
            }
        }

#pragma unroll
        for (int qg = 0; qg < 2; qg++)
#pragma unroll
            for (int nt = 0; nt < 4; nt++)
#pragma unroll
                for (int r = 0; r < 4; r++) s[qg][nt][r] *= scale;

        if (t == tdiag) {   // causal: mask s > q
#pragma unroll
            for (int qg = 0; qg < 2; qg++) {
                int q = q0 + qg * 16 + l16;
#pragma unroll
                for (int nt = 0; nt < 4; nt++)
#pragma unroll
                    for (int r = 0; r < 4; r++) {
                        int key = t * 64 + nt * 16 + quad * 4 + r;
                        if (key > q) s[qg][nt][r] = -1e30f;
                    }
            }
        }

        // per-lane softmax per q-group: in-lane tree + 2 cross-quad shuffles
#pragma unroll
        for (int qg = 0; qg < 2; qg++) {
            float m0 = fmaxf(fmaxf(s[qg][0][0], s[qg][0][1]), fmaxf(s[qg][0][2], s[qg][0][3]));
            float m1 = fmaxf(fmaxf(s[qg][1][0], s[qg][1][1]), fmaxf(s[qg][1][2], s[qg][1][3]));
            float m2 = fmaxf(fmaxf(s[qg][2][0], s[qg][2][1]), fmaxf(s[qg][2][2], s[qg][2][3]));
            float m3 = fmaxf(fmaxf(s[qg][3][0], s[qg][3][1]), fmaxf(s[qg][3][2], s[qg][3][3]));
            float mx = fmaxf(fmaxf(m0, m1), fmaxf(m2, m3));
            mx = fmaxf(mx, __shfl_xor(mx, 16));
            mx = fmaxf(mx, __shfl_xor(mx, 32));
            const float m_new = fmaxf(m_run[qg], mx);
            const float alpha = __expf(m_run[qg] - m_new);
            m_run[qg] = m_new;

            float rs = 0.f;
#pragma unroll
            for (int nt = 0; nt < 4; nt++) {
#pragma unroll
                for (int i = 0; i < 2; i++) {
                    float p0 = __expf(s[qg][nt][2 * i]     - m_new);
                    float p1 = __expf(s[qg][nt][2 * i + 1] - m_new);
                    rs += p0 + p1;
                    Pw[(qg * 16 + l16) * PROW + nt * 8 + quad * 2 + i] = pack2(p0, p1);
                }
            }
            rs += __shfl_xor(rs, 16);
            rs += __shfl_xor(rs, 32);
            l_run[qg] = l_run[qg] * alpha + rs;

#pragma unroll
            for (int ht = 0; ht < 4; ht++)
#pragma unroll
                for (int r = 0; r < 4; r++) o[qg * 4 + ht][r] *= alpha;
        }

        // O^T += V^T * P^T (V frags shared across q-groups)
#pragma unroll
        for (int ks = 0; ks < 2; ks++) {
#pragma unroll
            for (int qg = 0; qg < 2; qg++) {
                bf16x8 pB = __builtin_bit_cast(bf16x8,
                    *(const u16x8*)(&Pw[(qg * 16 + l16) * PROW + ks * 16 + quad * 4]));
#pragma unroll
                for (int ht = 0; ht < 4; ht++)
                    o[qg * 4 + ht] = __builtin_amdgcn_mfma_f32_16x16x32_bf16(
                        vf[ht * 2 + ks], pB, o[qg * 4 + ht], 0, 0, 0);
            }
        }
    }

    // ---- 4-way LSE merge (O partials bf16) ----
#pragma unroll
    for (int qg = 0; qg < 2; qg++) {
#pragma unroll
        for (int ht = 0; ht < 4; ht++)
#pragma unroll
            for (int r = 0; r < 4; r++)
                Om_[(wave * 32 + qg * 16 + l16) * OMS2 + ht * 16 + quad * 4 + r] =
                    f2bf(o[qg * 4 + ht][r]);
        if (quad == 0) {
            mred_[wave][qg * 16 + l16] = m_run[qg];
            lred_[wave][qg * 16 + l16] = l_run[qg];
        }
    }
    __syncthreads();

    // finalize: thread -> (q, h); coalesced out write
    const int hcol = tid & 63;
    const int qr0  = tid >> 6;   // 0..3
#pragma unroll
    for (int qq = 0; qq < 8; qq++) {
        const int q = qr0 + qq * 4;
        float M = -1e30f;
#pragma unroll
        for (int w = 0; w < 4; w++) M = fmaxf(M, mred_[w][q]);
        float lt = 0.f, ov = 0.f;
#pragma unroll
        for (int w = 0; w < 4; w++) {
            float e = __expf(mred_[w][q] - M);
            lt += e * lred_[w][q];
            ov += e * bf2f(Om_[(w * 32 + q) * OMS2 + hcol]);
        }
        out[((size_t)b * T_ + q0 + q) * H_ + hcol] = ov / lt;
    }
}

// ---------------------------------------------------------------------------
extern "C" void kernel_launch(void* const* d_in, const int* in_sizes, int n_in,
                              void* d_out, int out_size, void* d_ws, size_t ws_size,
                              hipStream_t stream) {
    const float* x  = (const float*)d_in[0];
    const float* Wq = (const float*)d_in[1];
    const float* Wk = (const float*)d_in[2];
    const float* Wv = (const float*)d_in[3];
    float* out = (float*)d_out;

    unsigned short* Qf  = (unsigned short*)d_ws;
    unsigned short* Kf  = Qf + (size_t)B_ * T_ * H_;
    unsigned short* Vf  = Kf + (size_t)B_ * T_ * H_;
    unsigned short* Wtf = Vf + (size_t)B_ * T_ * H_;

    cast_weights<<<(192 * C_) / 256, 256, 0, stream>>>(Wq, Wk, Wv, Wtf);
    qkv_proj<<<B_ * T_ / 16, 256, 0, stream>>>(x, Wtf, Qf, Kf, Vf);
    attn<<<B_ * (T_ / 32), 256, 0, stream>>>(Qf, Kf, Vf, out);
}